// Round 2
// baseline (830.788 us; speedup 1.0000x reference)
//
#include <hip/hip_runtime.h>

typedef __attribute__((ext_vector_type(8))) short bf16x8;
typedef __attribute__((ext_vector_type(4))) float f32x4;

__device__ __forceinline__ float bf2f(short s) {
    union { unsigned int i; float f; } v;
    v.i = ((unsigned int)(unsigned short)s) << 16;
    return v.f;
}
__device__ __forceinline__ short f2bf(float f) {
    unsigned int x = __float_as_uint(f);
    unsigned int r = (x + 0x7fffu + ((x >> 16) & 1u)) >> 16;
    return (short)r;
}

// ---------------------------------------------------------------------------
// Transpose f32 -> bf16 with zero-pad of output rows:
// in: R x C (row-major f32) -> out: Cout x R bf16, out[c][r] = (c<C)? in[r][c] : 0
// grid = (R/64, Cout/64), block = 256
// ---------------------------------------------------------------------------
__global__ __launch_bounds__(256) void transpose_cvt(
    const float* __restrict__ in, short* __restrict__ out,
    int R, int C, int Cout)
{
    __shared__ short tile[64][65];
    const int r0 = blockIdx.x << 6;
    const int c0 = blockIdx.y << 6;
    const int t = threadIdx.x;
#pragma unroll
    for (int i = 0; i < 16; ++i) {
        int idx = t + (i << 8);
        int rr = idx >> 6, cc = idx & 63;
        int c = c0 + cc;
        tile[rr][cc] = (c < C) ? f2bf(in[(size_t)(r0 + rr) * C + c]) : (short)0;
    }
    __syncthreads();
#pragma unroll
    for (int i = 0; i < 16; ++i) {
        int idx = t + (i << 8);
        int cc = idx >> 6, rr = idx & 63;
        out[(size_t)(c0 + cc) * R + r0 + rr] = tile[rr][cc];
    }
}

// ---------------------------------------------------------------------------
// C[M,N] = act(A[M,K] @ Bt[N,K]^T + bias[N]), fp32 accumulate, bf16 out.
// A is f32 (A_F32=1) or bf16 (A_F32=0); Bt is pre-transposed bf16 weights.
// Tile 64x64, BK=64, block=256 (4 waves; wave w -> rows 16w..16w+15).
// grid = (M/64, N/64).
// ---------------------------------------------------------------------------
template<int A_F32>
__global__ __launch_bounds__(256) void gemm_bt(
    const void* __restrict__ Ap, int lda,
    const short* __restrict__ Bt, int ldb,
    const float* __restrict__ bias,      // may be null (f32)
    short* __restrict__ C, int ldc,
    int K, int relu)
{
    __shared__ short As[64][72];
    __shared__ short Bs[64][72];
    const int t = threadIdx.x;
    const int wave = t >> 6;
    const int lane = t & 63;
    const int m0 = blockIdx.x << 6;
    const int n0 = blockIdx.y << 6;

    // staging: thread t covers row rr = t>>2, 16 elements at kc = (t&3)*16
    const int rr = t >> 2;
    const int kc = (t & 3) << 4;
    const float* apf = (const float*)Ap + (size_t)(m0 + rr) * lda + kc;
    const short* aps = (const short*)Ap + (size_t)(m0 + rr) * lda + kc;
    const short* bp  = Bt + (size_t)(n0 + rr) * ldb + kc;

    f32x4 acc[4];
#pragma unroll
    for (int i = 0; i < 4; ++i) acc[i] = (f32x4){0.f, 0.f, 0.f, 0.f};

    const int ml = lane & 15;
    const int kq = (lane >> 4) << 3;

    for (int k0 = 0; k0 < K; k0 += 64) {
        bf16x8 a0, a1;
        if (A_F32) {
            float4 x0 = *(const float4*)(apf + k0);
            float4 x1 = *(const float4*)(apf + k0 + 4);
            float4 x2 = *(const float4*)(apf + k0 + 8);
            float4 x3 = *(const float4*)(apf + k0 + 12);
            a0[0] = f2bf(x0.x); a0[1] = f2bf(x0.y); a0[2] = f2bf(x0.z); a0[3] = f2bf(x0.w);
            a0[4] = f2bf(x1.x); a0[5] = f2bf(x1.y); a0[6] = f2bf(x1.z); a0[7] = f2bf(x1.w);
            a1[0] = f2bf(x2.x); a1[1] = f2bf(x2.y); a1[2] = f2bf(x2.z); a1[3] = f2bf(x2.w);
            a1[4] = f2bf(x3.x); a1[5] = f2bf(x3.y); a1[6] = f2bf(x3.z); a1[7] = f2bf(x3.w);
        } else {
            a0 = *(const bf16x8*)(aps + k0);
            a1 = *(const bf16x8*)(aps + k0 + 8);
        }
        bf16x8 b0 = *(const bf16x8*)(bp + k0);
        bf16x8 b1 = *(const bf16x8*)(bp + k0 + 8);
        __syncthreads();
        *(bf16x8*)&As[rr][kc]     = a0;
        *(bf16x8*)&As[rr][kc + 8] = a1;
        *(bf16x8*)&Bs[rr][kc]     = b0;
        *(bf16x8*)&Bs[rr][kc + 8] = b1;
        __syncthreads();
#pragma unroll
        for (int ks = 0; ks < 64; ks += 32) {
            bf16x8 af = *(const bf16x8*)&As[(wave << 4) + ml][ks + kq];
#pragma unroll
            for (int nb = 0; nb < 4; ++nb) {
                bf16x8 bfr = *(const bf16x8*)&Bs[(nb << 4) + ml][ks + kq];
                acc[nb] = __builtin_amdgcn_mfma_f32_16x16x32_bf16(af, bfr, acc[nb], 0, 0, 0);
            }
        }
    }

    // C/D layout: col = lane&15, row = (lane>>4)*4 + reg
    const int ql = lane >> 4;
#pragma unroll
    for (int reg = 0; reg < 4; ++reg) {
        int r = m0 + (wave << 4) + (ql << 2) + reg;
#pragma unroll
        for (int nb = 0; nb < 4; ++nb) {
            int c = n0 + (nb << 4) + ml;
            float v = acc[nb][reg];
            if (bias) v += bias[c];
            if (relu) v = fmaxf(v, 0.f);
            C[(size_t)r * ldc + c] = f2bf(v);
        }
    }
}

// ---------------------------------------------------------------------------
// Fused final stage, 64 relation rows per block:
//   A'[r,k] = bf16( (H[p0[r],k] + T[p1[r],k] + b_cat[k]) * U[r,k] )
//   acc = A' @ Wt^T        (Wt: 64x4096 = zero-padded w_ctx^T, bf16)
//   out[r,c] = acc + b_ctx[c] + freq[obj[p0]*151+obj[p1], c]   (c < 51, f32)
// grid = 512, block = 256.
// ---------------------------------------------------------------------------
__global__ __launch_bounds__(256) void fused_rel(
    const float* __restrict__ U,        // 32768 x 4096 f32
    const short* __restrict__ Hm,       // 1280 x 4096 bf16
    const short* __restrict__ Tm,       // 1280 x 4096 bf16
    const short* __restrict__ Wt,       // 64 x 4096 bf16
    const float* __restrict__ bcat,     // 4096 f32
    const float* __restrict__ bctx,     // 51 f32
    const float* __restrict__ freq,     // 22801 x 51 f32
    const int* __restrict__ obj_preds,  // 1280 int32
    const int* __restrict__ pair_idx,   // 32768 x 2 int32
    float* __restrict__ out)            // 32768 x 51 f32
{
    __shared__ short As[64][72];
    __shared__ short Bs[64][72];
    const int t = threadIdx.x;
    const int wave = t >> 6;
    const int lane = t & 63;
    const int r0 = blockIdx.x << 6;

    const int rr = t >> 2;
    const int kc = (t & 3) << 4;

    const int r = r0 + rr;
    const int p0 = pair_idx[2 * r];
    const int p1 = pair_idx[2 * r + 1];

    const float* up = U + (size_t)r * 4096 + kc;
    const short* hp = Hm + (size_t)p0 * 4096 + kc;
    const short* tp = Tm + (size_t)p1 * 4096 + kc;
    const short* wp = Wt + (size_t)rr * 4096 + kc;
    const float* bp = bcat + kc;

    f32x4 acc[4];
#pragma unroll
    for (int i = 0; i < 4; ++i) acc[i] = (f32x4){0.f, 0.f, 0.f, 0.f};

    const int ml = lane & 15;
    const int kq = (lane >> 4) << 3;

    for (int k0 = 0; k0 < 4096; k0 += 64) {
        float4 u0 = *(const float4*)(up + k0);
        float4 u1 = *(const float4*)(up + k0 + 4);
        float4 u2 = *(const float4*)(up + k0 + 8);
        float4 u3 = *(const float4*)(up + k0 + 12);
        float4 c0 = *(const float4*)(bp + k0);
        float4 c1 = *(const float4*)(bp + k0 + 4);
        float4 c2 = *(const float4*)(bp + k0 + 8);
        float4 c3 = *(const float4*)(bp + k0 + 12);
        bf16x8 h0 = *(const bf16x8*)(hp + k0);
        bf16x8 h1 = *(const bf16x8*)(hp + k0 + 8);
        bf16x8 t0 = *(const bf16x8*)(tp + k0);
        bf16x8 t1 = *(const bf16x8*)(tp + k0 + 8);
        bf16x8 w0 = *(const bf16x8*)(wp + k0);
        bf16x8 w1 = *(const bf16x8*)(wp + k0 + 8);

        float uu[16] = {u0.x,u0.y,u0.z,u0.w, u1.x,u1.y,u1.z,u1.w,
                        u2.x,u2.y,u2.z,u2.w, u3.x,u3.y,u3.z,u3.w};
        float bb[16] = {c0.x,c0.y,c0.z,c0.w, c1.x,c1.y,c1.z,c1.w,
                        c2.x,c2.y,c2.z,c2.w, c3.x,c3.y,c3.z,c3.w};

        bf16x8 a0, a1;
#pragma unroll
        for (int j = 0; j < 8; ++j) {
            a0[j] = f2bf((bf2f(h0[j]) + bf2f(t0[j]) + bb[j])     * uu[j]);
            a1[j] = f2bf((bf2f(h1[j]) + bf2f(t1[j]) + bb[8 + j]) * uu[8 + j]);
        }
        __syncthreads();
        *(bf16x8*)&As[rr][kc]     = a0;
        *(bf16x8*)&As[rr][kc + 8] = a1;
        *(bf16x8*)&Bs[rr][kc]     = w0;
        *(bf16x8*)&Bs[rr][kc + 8] = w1;
        __syncthreads();
#pragma unroll
        for (int ks = 0; ks < 64; ks += 32) {
            bf16x8 af = *(const bf16x8*)&As[(wave << 4) + ml][ks + kq];
#pragma unroll
            for (int nb = 0; nb < 4; ++nb) {
                bf16x8 bfr = *(const bf16x8*)&Bs[(nb << 4) + ml][ks + kq];
                acc[nb] = __builtin_amdgcn_mfma_f32_16x16x32_bf16(af, bfr, acc[nb], 0, 0, 0);
            }
        }
    }

    const int ql = lane >> 4;
#pragma unroll
    for (int reg = 0; reg < 4; ++reg) {
        int rm = r0 + (wave << 4) + (ql << 2) + reg;
        int q0 = pair_idx[2 * rm];
        int q1 = pair_idx[2 * rm + 1];
        int code = obj_preds[q0] * 151 + obj_preds[q1];
        const float* fr = freq + (size_t)code * 51;
#pragma unroll
        for (int nb = 0; nb < 4; ++nb) {
            int c = (nb << 4) + ml;
            if (c < 51) {
                out[(size_t)rm * 51 + c] = acc[nb][reg] + bctx[c] + fr[c];
            }
        }
    }
}

// ---------------------------------------------------------------------------
extern "C" void kernel_launch(void* const* d_in, const int* in_sizes, int n_in,
                              void* d_out, int out_size, void* d_ws, size_t ws_size,
                              hipStream_t stream)
{
    (void)in_sizes; (void)n_in; (void)out_size; (void)ws_size;

    const float* edge_ctx = (const float*)d_in[0];   // 1280 x 512
    const float* unionf   = (const float*)d_in[1];   // 32768 x 4096
    const float* w_emb    = (const float*)d_in[2];   // 512 x 1024
    const float* b_emb    = (const float*)d_in[3];   // 1024
    const float* w_cat    = (const float*)d_in[4];   // 1024 x 4096
    const float* b_cat    = (const float*)d_in[5];   // 4096
    const float* w_ctx    = (const float*)d_in[6];   // 4096 x 51
    const float* b_ctx    = (const float*)d_in[7];   // 51
    const float* freq     = (const float*)d_in[8];   // 22801 x 51
    const int*   obj_pred = (const int*)d_in[9];     // 1280
    const int*   pair_idx = (const int*)d_in[10];    // 32768 x 2
    float* out = (float*)d_out;                      // 32768 x 51

    char* ws = (char*)d_ws;
    short* WembT    = (short*)(ws);                     // 1024 x 512  bf16 (1 MiB)
    short* WcatT    = (short*)(ws + (1ull  << 20));     // 4096 x 1024 bf16 (8 MiB)
    short* Wt       = (short*)(ws + (9ull  << 20));     // 64 x 4096   bf16 (0.5 MiB)
    short* edge_rep = (short*)(ws + (10ull << 20));     // 1280 x 1024 bf16 (2.5 MiB)
    short* Hbuf     = (short*)(ws + (13ull << 20));     // 1280 x 4096 bf16 (10 MiB)
    short* Tbuf     = (short*)(ws + (23ull << 20));     // 1280 x 4096 bf16 (10 MiB)

    // 1-3: weight transpose + f32->bf16 convert
    transpose_cvt<<<dim3(8, 16),  256, 0, stream>>>(w_emb, WembT, 512, 1024, 1024);
    transpose_cvt<<<dim3(16, 64), 256, 0, stream>>>(w_cat, WcatT, 1024, 4096, 4096);
    transpose_cvt<<<dim3(64, 1),  256, 0, stream>>>(w_ctx, Wt, 4096, 51, 64);

    // 4: edge_rep = relu(edge_ctx @ w_post_emb + b_post_emb)   (1280 x 1024)
    gemm_bt<1><<<dim3(20, 16), 256, 0, stream>>>(edge_ctx, 512, WembT, 512,
                                                 b_emb, edge_rep, 1024, 512, 1);

    // 5: H = edge_rep[:, :512] @ w_post_cat[:512, :]   (1280 x 4096)
    gemm_bt<0><<<dim3(20, 64), 256, 0, stream>>>(edge_rep, 1024, WcatT, 1024,
                                                 nullptr, Hbuf, 4096, 512, 0);
    // 6: T = edge_rep[:, 512:] @ w_post_cat[512:, :]   (1280 x 4096)
    gemm_bt<0><<<dim3(20, 64), 256, 0, stream>>>(edge_rep + 512, 1024, WcatT + 512, 1024,
                                                 nullptr, Tbuf, 4096, 512, 0);

    // 7: fused (H[p0]+T[p1]+b_cat)*union @ w_ctx + b_ctx + freq  -> out (f32)
    fused_rel<<<dim3(512), 256, 0, stream>>>(unionf, Hbuf, Tbuf, Wt, b_cat, b_ctx,
                                             freq, obj_pred, pair_idx, out);
}